// Round 6
// baseline (730.243 us; speedup 1.0000x reference)
//
#include <hip/hip_runtime.h>
#include <hip/hip_bf16.h>
#include <math.h>

#define B_SZ   4096
#define H_LEN  256
#define D_DIM  128
#define K_HEADS 4
#define H1_DIM 512
#define H2_DIM 256
#define TPAD   132    // tile row stride (floats), 16B-aligned

typedef __attribute__((ext_vector_type(8))) short bf16x8;   // 8 bf16 (4 VGPRs)
typedef __attribute__((ext_vector_type(4))) float f32x4;

// ---------------------------------------------------------------------------
// Kernel 1: barrier-free wave-private multi-interest extraction.
// Blocks [0,4096): block b = sample b; wave w owns rows [64w, 64w+64) in
// 4 chunks of 16. No __syncthreads in the hot loop (wave-synchronous LDS),
// so chunk c+1's gather overlaps chunk c's pooling (no vmcnt drain).
// Blocks [4096,5120): bf16 weight transpose for the MFMA MLP tail.
// ---------------------------------------------------------------------------
__global__ __launch_bounds__(256, 4) void interest_kernel(
    const int*   __restrict__ cand_ids,   // (B,)
    const int*   __restrict__ hist,       // (B, H)
    const float* __restrict__ table,      // (NUM_ITEMS, D)
    const float* __restrict__ Wp,         // (D, K) row-major
    const float* __restrict__ W1,         // (2D, H1)
    const float* __restrict__ W2,         // (H1, H2)
    __hip_bfloat16* __restrict__ W1t,     // out (H1, 2D) bf16
    __hip_bfloat16* __restrict__ W2t,     // out (H2, H1) bf16
    __hip_bfloat16* __restrict__ Xbf)     // out (B, 2D) bf16: [selected | cand]
{
    // ---- weight-conversion blocks ----
    if (blockIdx.x >= B_SZ) {
        int idx = (blockIdx.x - B_SZ) * 256 + threadIdx.x;
        if (idx < 2 * D_DIM * H1_DIM) {              // W1t[n][k] = W1[k][n]
            int n = idx >> 8, k = idx & 255;
            W1t[idx] = __float2bfloat16(W1[k * H1_DIM + n]);
        } else {                                     // W2t[n][k] = W2[k][n]
            int j = idx - 2 * D_DIM * H1_DIM;
            int n = j >> 9, k = j & 511;
            W2t[j] = __float2bfloat16(W2[k * H2_DIM + n]);
        }
        return;
    }

    __shared__ float tile[4 * 16 * TPAD];  // 33792 B, wave-private regions
    __shared__ float wpt[K_HEADS * D_DIM]; // Wp^T [k][d]            2 KB
    __shared__ float exps4[4 * 16 * 4];    // e[wave][row][k]        1 KB
    __shared__ float candv[D_DIM];         //                        512 B
    __shared__ float ivbuf[D_DIM * 4];     // interest vecs [d][k]   2 KB
    __shared__ float lsumW[16];            // per-wave denom [w][k]
    __shared__ float simred[4][K_HEADS];
    __shared__ int   bestk;

    const int b    = blockIdx.x;
    const int t    = threadIdx.x;
    const int lane = t & 63, w = t >> 6;
    const int r    = lane >> 2;            // row within chunk (0..15)
    const int q    = lane & 3;             // 4 lanes per row, 32 dims each
    const int d0   = lane, d1 = lane + 64; // pooling dims
    const int wtile = w * (16 * TPAD);     // wave-private tile base (floats)

    // --- stage Wp^T + candidate row; single barrier before the loop ---
    if (t < D_DIM) {
        float4 w4 = ((const float4*)Wp)[t];   // Wp[d=t][0..3]
        wpt[0 * D_DIM + t] = w4.x;
        wpt[1 * D_DIM + t] = w4.y;
        wpt[2 * D_DIM + t] = w4.z;
        wpt[3 * D_DIM + t] = w4.w;
    }
    const int cand = cand_ids[b];
    if (t >= 128 && t < 160) {
        int c = t - 128;
        ((float4*)candv)[c] = ((const float4*)(table + (long long)cand * D_DIM))[c];
    }
    __syncthreads();

    // --- row ids for all 4 chunks (independent loads, issued up front) ---
    int ids[4];
    {
        const long long hb = (long long)b * H_LEN + w * 64 + r;
        #pragma unroll
        for (int c = 0; c < 4; ++c) ids[c] = hist[hb + c * 16];
    }

    float accA[4] = {0.f, 0.f, 0.f, 0.f};  // heads, dim d0
    float accB[4] = {0.f, 0.f, 0.f, 0.f};  // heads, dim d1
    float lsum[4] = {0.f, 0.f, 0.f, 0.f};  // per-lane denom partial

    // prefetch chunk 0
    float4 v[8];
    {
        const float* rp = table + (long long)ids[0] * D_DIM + (q << 2);
        #pragma unroll
        for (int j = 0; j < 8; ++j) v[j] = *(const float4*)(rp + j * 16);
    }

    #pragma unroll
    for (int c = 0; c < 4; ++c) {
        // --- scores for my row + stage row into wave-private tile ---
        float s0 = 0.f, s1 = 0.f, s2 = 0.f, s3 = 0.f;
        #pragma unroll
        for (int j = 0; j < 8; ++j) {
            const int cb = (q << 2) + (j << 4);
            float4 va = v[j];
            float4 w0 = *(const float4*)(wpt + 0 * D_DIM + cb);
            float4 w1 = *(const float4*)(wpt + 1 * D_DIM + cb);
            float4 w2 = *(const float4*)(wpt + 2 * D_DIM + cb);
            float4 w3 = *(const float4*)(wpt + 3 * D_DIM + cb);
            s0 += va.x * w0.x + va.y * w0.y + va.z * w0.z + va.w * w0.w;
            s1 += va.x * w1.x + va.y * w1.y + va.z * w1.z + va.w * w1.w;
            s2 += va.x * w2.x + va.y * w2.y + va.z * w2.z + va.w * w2.w;
            s3 += va.x * w3.x + va.y * w3.y + va.z * w3.z + va.w * w3.w;
            *(float4*)(tile + wtile + r * TPAD + cb) = va;
        }

        // --- prefetch next chunk (stays in flight: no barrier ahead) ---
        float4 vn[8];
        if (c < 3) {
            const float* rp = table + (long long)ids[c + 1] * D_DIM + (q << 2);
            #pragma unroll
            for (int j = 0; j < 8; ++j) vn[j] = *(const float4*)(rp + j * 16);
        }

        // --- combine 4 q-lanes of the row; exp ---
        s0 += __shfl_xor(s0, 1); s0 += __shfl_xor(s0, 2);
        s1 += __shfl_xor(s1, 1); s1 += __shfl_xor(s1, 2);
        s2 += __shfl_xor(s2, 1); s2 += __shfl_xor(s2, 2);
        s3 += __shfl_xor(s3, 1); s3 += __shfl_xor(s3, 2);
        float e0 = expf(s0), e1 = expf(s1), e2 = expf(s2), e3 = expf(s3);
        if (q == 0) ((float4*)exps4)[w * 16 + r] = make_float4(e0, e1, e2, e3);
        lsum[0] += e0; lsum[1] += e1; lsum[2] += e2; lsum[3] += e3;

        // --- pooling over my wave's 16 chunk rows (wave-local LDS) ---
        #pragma unroll
        for (int h = 0; h < 16; ++h) {
            float4 e4 = ((const float4*)exps4)[w * 16 + h];   // broadcast
            float  p0 = tile[wtile + h * TPAD + d0];
            float  p1 = tile[wtile + h * TPAD + d1];
            accA[0] += e4.x * p0; accA[1] += e4.y * p0;
            accA[2] += e4.z * p0; accA[3] += e4.w * p0;
            accB[0] += e4.x * p1; accB[1] += e4.y * p1;
            accB[2] += e4.z * p1; accB[3] += e4.w * p1;
        }

        if (c < 3) {
            #pragma unroll
            for (int j = 0; j < 8; ++j) v[j] = vn[j];
        }
    }

    // --- wave-partial denominator: sum 16 r-classes (q-copies identical) ---
    #pragma unroll
    for (int off = 4; off <= 32; off <<= 1) {
        lsum[0] += __shfl_xor(lsum[0], off);
        lsum[1] += __shfl_xor(lsum[1], off);
        lsum[2] += __shfl_xor(lsum[2], off);
        lsum[3] += __shfl_xor(lsum[3], off);
    }

    // --- write wave partials into own tile region; one true barrier ---
    float* Pw = tile + wtile;   // 512 floats: P[w][dim] as float4 per dim
    ((float4*)Pw)[d0] = make_float4(accA[0], accA[1], accA[2], accA[3]);
    ((float4*)Pw)[d1] = make_float4(accB[0], accB[1], accB[2], accB[3]);
    if (lane == 0) ((float4*)lsumW)[w] = make_float4(lsum[0], lsum[1], lsum[2], lsum[3]);
    __syncthreads();

    // --- combine wave partials, normalize, sims ---
    float s0 = 0.f, s1 = 0.f, s2 = 0.f, s3 = 0.f;
    if (t < 128) {
        const int d = t;
        float4 p0 = ((const float4*)(tile + 0 * 16 * TPAD))[d];
        float4 p1 = ((const float4*)(tile + 1 * 16 * TPAD))[d];
        float4 p2 = ((const float4*)(tile + 2 * 16 * TPAD))[d];
        float4 p3 = ((const float4*)(tile + 3 * 16 * TPAD))[d];
        float4 L0 = ((const float4*)lsumW)[0];
        float4 L1 = ((const float4*)lsumW)[1];
        float4 L2 = ((const float4*)lsumW)[2];
        float4 L3 = ((const float4*)lsumW)[3];
        float i0 = 1.f / (L0.x + L1.x + L2.x + L3.x);
        float i1 = 1.f / (L0.y + L1.y + L2.y + L3.y);
        float i2 = 1.f / (L0.z + L1.z + L2.z + L3.z);
        float i3 = 1.f / (L0.w + L1.w + L2.w + L3.w);
        float a0 = (((p0.x + p1.x) + p2.x) + p3.x) * i0;
        float a1 = (((p0.y + p1.y) + p2.y) + p3.y) * i1;
        float a2 = (((p0.z + p1.z) + p2.z) + p3.z) * i2;
        float a3 = (((p0.w + p1.w) + p2.w) + p3.w) * i3;
        ((float4*)ivbuf)[d] = make_float4(a0, a1, a2, a3);
        float cd = candv[d];
        s0 = a0 * cd; s1 = a1 * cd; s2 = a2 * cd; s3 = a3 * cd;
    }
    #pragma unroll
    for (int off = 32; off >= 1; off >>= 1) {
        s0 += __shfl_xor(s0, off);
        s1 += __shfl_xor(s1, off);
        s2 += __shfl_xor(s2, off);
        s3 += __shfl_xor(s3, off);
    }
    if (lane == 0) {
        simred[w][0] = s0; simred[w][1] = s1;
        simred[w][2] = s2; simred[w][3] = s3;
    }
    __syncthreads();

    if (t == 0) {
        float sim[4];
        #pragma unroll
        for (int k = 0; k < 4; ++k)
            sim[k] = simred[0][k] + simred[1][k] + simred[2][k] + simred[3][k];
        int best = 0;
        #pragma unroll
        for (int k = 1; k < 4; ++k) if (sim[k] > sim[best]) best = k;  // first-max
        bestk = best;
    }
    __syncthreads();

    __hip_bfloat16* xrow = Xbf + (long long)b * (2 * D_DIM);
    if (t < 128) xrow[t] = __float2bfloat16(ivbuf[t * 4 + bestk]);
    else         xrow[t] = __float2bfloat16(candv[t - 128]);
}

// ---------------------------------------------------------------------------
// MFMA bf16 GEMM: C(M,N) = relu(A(M,K) @ B(K,N) + bias). B passed transposed
// (N,K) row-major. One wave = one 16x16 C tile; no LDS; direct b128 frag
// loads. A-frag: A[m=lane&15][k=quad*8+j]; B-frag: Bt[n=lane&15][k=quad*8+j];
// C: col=lane&15, row=quad*4+reg (verified layouts).
// ---------------------------------------------------------------------------
template<int N, int K, bool OUT_BF16>
__global__ __launch_bounds__(256) void mfma_mlp(
    const __hip_bfloat16* __restrict__ A,    // (M, K)
    const __hip_bfloat16* __restrict__ Bt,   // (N, K)
    const float* __restrict__ bias,          // (N,)
    void* __restrict__ Cout)                 // (M, N)
{
    const int t    = threadIdx.x;
    const int wave = t >> 6, lane = t & 63;
    const int lm   = lane & 15, quad = lane >> 4;
    const int n0   = blockIdx.x * 16;
    const int m0   = blockIdx.y * 64 + wave * 16;

    const __hip_bfloat16* Ap = A  + (long long)(m0 + lm) * K + quad * 8;
    const __hip_bfloat16* Bp = Bt + (long long)(n0 + lm) * K + quad * 8;

    f32x4 acc = {0.f, 0.f, 0.f, 0.f};
    for (int kc = 0; kc < K; kc += 256) {
        bf16x8 af[8], bfr[8];
        #pragma unroll
        for (int it = 0; it < 8; ++it) {
            af[it]  = *(const bf16x8*)(Ap + kc + it * 32);
            bfr[it] = *(const bf16x8*)(Bp + kc + it * 32);
        }
        #pragma unroll
        for (int it = 0; it < 8; ++it)
            acc = __builtin_amdgcn_mfma_f32_16x16x32_bf16(af[it], bfr[it], acc, 0, 0, 0);
    }

    const int n  = n0 + lm;
    const float bv = bias[n];
    #pragma unroll
    for (int i = 0; i < 4; ++i) {
        int m = m0 + quad * 4 + i;
        float v = fmaxf(acc[i] + bv, 0.f);
        if (OUT_BF16)
            ((__hip_bfloat16*)Cout)[(long long)m * N + n] = __float2bfloat16(v);
        else
            ((float*)Cout)[(long long)m * N + n] = v;
    }
}

// ---------------------------------------------------------------------------
// Kernel 4: out[b] = sigmoid(h2[b] . W3 + b3)
// ---------------------------------------------------------------------------
__global__ __launch_bounds__(256) void head_kernel(
    const float* __restrict__ H2buf,   // (B, 256) fp32
    const float* __restrict__ W3,      // (256, 1)
    const float* __restrict__ b3,
    float*       __restrict__ out)     // (B,)
{
    const int b = blockIdx.x * 256 + threadIdx.x;
    const float4* hp = (const float4*)(H2buf + (long long)b * H2_DIM);
    const float4* wp = (const float4*)W3;
    float acc = 0.f;
    #pragma unroll 8
    for (int i = 0; i < H2_DIM / 4; ++i) {
        float4 h = hp[i], wv = wp[i];
        acc += h.x * wv.x + h.y * wv.y + h.z * wv.z + h.w * wv.w;
    }
    float z = acc + b3[0];
    out[b] = 1.f / (1.f + expf(-z));
}

// ---------------------------------------------------------------------------
extern "C" void kernel_launch(void* const* d_in, const int* in_sizes, int n_in,
                              void* d_out, int out_size, void* d_ws, size_t ws_size,
                              hipStream_t stream) {
    const int*   cand  = (const int*)  d_in[1];
    const int*   hist  = (const int*)  d_in[2];
    const float* table = (const float*)d_in[3];
    const float* Wp    = (const float*)d_in[4];
    const float* W1    = (const float*)d_in[5];
    const float* b1    = (const float*)d_in[6];
    const float* W2    = (const float*)d_in[7];
    const float* b2    = (const float*)d_in[8];
    const float* W3    = (const float*)d_in[9];
    const float* b3    = (const float*)d_in[10];
    float* out = (float*)d_out;

    // ws layout (16B-aligned regions)
    char* p = (char*)d_ws;
    __hip_bfloat16* Xbf  = (__hip_bfloat16*)p;                  p += (size_t)B_SZ * 2 * D_DIM * 2;  // 2 MB
    __hip_bfloat16* Hc1  = (__hip_bfloat16*)p;                  p += (size_t)B_SZ * H1_DIM * 2;     // 4 MB
    float*          Hc2  = (float*)p;                           p += (size_t)B_SZ * H2_DIM * 4;     // 4 MB
    __hip_bfloat16* W1t  = (__hip_bfloat16*)p;                  p += (size_t)H1_DIM * 2 * D_DIM * 2;// 512 KB
    __hip_bfloat16* W2t  = (__hip_bfloat16*)p;                                                      // 512 KB

    // interest blocks [0,4096) + weight-convert blocks [4096,5120)
    interest_kernel<<<B_SZ + 1024, 256, 0, stream>>>(
        cand, hist, table, Wp, W1, W2, W1t, W2t, Xbf);
    mfma_mlp<H1_DIM, 2 * D_DIM, true><<<dim3(H1_DIM / 16, B_SZ / 64), 256, 0, stream>>>(
        Xbf, W1t, b1, Hc1);
    mfma_mlp<H2_DIM, H1_DIM, false><<<dim3(H2_DIM / 16, B_SZ / 64), 256, 0, stream>>>(
        Hc1, W2t, b2, Hc2);
    head_kernel<<<B_SZ / 256, 256, 0, stream>>>(Hc2, W3, b3, out);
}

// Round 7
// 534.945 us; speedup vs baseline: 1.3651x; 1.3651x over previous
//
#include <hip/hip_runtime.h>
#include <hip/hip_bf16.h>
#include <math.h>

#define B_SZ   4096
#define H_LEN  256
#define D_DIM  128
#define K_HEADS 4
#define H1_DIM 512
#define H2_DIM 256
#define TPAD   132    // tile row stride (floats), 16B-aligned

typedef __attribute__((ext_vector_type(8))) short bf16x8;   // 8 bf16 (4 VGPRs)
typedef __attribute__((ext_vector_type(4))) float f32x4;

// ---------------------------------------------------------------------------
// Kernel 1: barrier-free wave-private multi-interest extraction.
// Blocks [0,4096): block b = sample b; wave w owns rows [64w, 64w+64) in
// 4 chunks of 16. No __syncthreads in the hot loop (wave-synchronous LDS),
// so chunk c+1's gather overlaps chunk c's pooling (no vmcnt drain).
// __launch_bounds__(256,2): 128-VGPR budget so the double-buffer prefetch
// stays in registers (round 6's (256,4)=64-VGPR cap spilled 1.1 GB to
// scratch). LDS (39 KB -> 4 blocks/CU) is the binding occupancy cap either
// way, so this costs nothing.
// Blocks [4096,5120): bf16 weight transpose for the MFMA MLP tail.
// ---------------------------------------------------------------------------
__global__ __launch_bounds__(256, 2) void interest_kernel(
    const int*   __restrict__ cand_ids,   // (B,)
    const int*   __restrict__ hist,       // (B, H)
    const float* __restrict__ table,      // (NUM_ITEMS, D)
    const float* __restrict__ Wp,         // (D, K) row-major
    const float* __restrict__ W1,         // (2D, H1)
    const float* __restrict__ W2,         // (H1, H2)
    __hip_bfloat16* __restrict__ W1t,     // out (H1, 2D) bf16
    __hip_bfloat16* __restrict__ W2t,     // out (H2, H1) bf16
    __hip_bfloat16* __restrict__ Xbf)     // out (B, 2D) bf16: [selected | cand]
{
    // ---- weight-conversion blocks ----
    if (blockIdx.x >= B_SZ) {
        int idx = (blockIdx.x - B_SZ) * 256 + threadIdx.x;
        if (idx < 2 * D_DIM * H1_DIM) {              // W1t[n][k] = W1[k][n]
            int n = idx >> 8, k = idx & 255;
            W1t[idx] = __float2bfloat16(W1[k * H1_DIM + n]);
        } else {                                     // W2t[n][k] = W2[k][n]
            int j = idx - 2 * D_DIM * H1_DIM;
            int n = j >> 9, k = j & 511;
            W2t[j] = __float2bfloat16(W2[k * H2_DIM + n]);
        }
        return;
    }

    __shared__ float tile[4 * 16 * TPAD];  // 33792 B, wave-private regions
    __shared__ float wpt[K_HEADS * D_DIM]; // Wp^T [k][d]            2 KB
    __shared__ float exps4[4 * 16 * 4];    // e[wave][row][k]        1 KB
    __shared__ float candv[D_DIM];         //                        512 B
    __shared__ float ivbuf[D_DIM * 4];     // interest vecs [d][k]   2 KB
    __shared__ float lsumW[16];            // per-wave denom [w][k]
    __shared__ float simred[4][K_HEADS];
    __shared__ int   bestk;

    const int b    = blockIdx.x;
    const int t    = threadIdx.x;
    const int lane = t & 63, w = t >> 6;
    const int r    = lane >> 2;            // row within chunk (0..15)
    const int q    = lane & 3;             // 4 lanes per row, 32 dims each
    const int d0   = lane, d1 = lane + 64; // pooling dims
    const int wtile = w * (16 * TPAD);     // wave-private tile base (floats)

    // --- stage Wp^T + candidate row; single barrier before the loop ---
    if (t < D_DIM) {
        float4 w4 = ((const float4*)Wp)[t];   // Wp[d=t][0..3]
        wpt[0 * D_DIM + t] = w4.x;
        wpt[1 * D_DIM + t] = w4.y;
        wpt[2 * D_DIM + t] = w4.z;
        wpt[3 * D_DIM + t] = w4.w;
    }
    const int cand = cand_ids[b];
    if (t >= 128 && t < 160) {
        int c = t - 128;
        ((float4*)candv)[c] = ((const float4*)(table + (long long)cand * D_DIM))[c];
    }
    __syncthreads();

    // --- row ids for all 4 chunks (independent loads, issued up front) ---
    int ids[4];
    {
        const long long hb = (long long)b * H_LEN + w * 64 + r;
        #pragma unroll
        for (int c = 0; c < 4; ++c) ids[c] = hist[hb + c * 16];
    }

    float accA[4] = {0.f, 0.f, 0.f, 0.f};  // heads, dim d0
    float accB[4] = {0.f, 0.f, 0.f, 0.f};  // heads, dim d1
    float lsum[4] = {0.f, 0.f, 0.f, 0.f};  // per-lane denom partial

    // prefetch chunk 0
    float4 v[8];
    {
        const float* rp = table + (long long)ids[0] * D_DIM + (q << 2);
        #pragma unroll
        for (int j = 0; j < 8; ++j) v[j] = *(const float4*)(rp + j * 16);
    }

    #pragma unroll
    for (int c = 0; c < 4; ++c) {
        // --- scores for my row + stage row into wave-private tile ---
        float s0 = 0.f, s1 = 0.f, s2 = 0.f, s3 = 0.f;
        #pragma unroll
        for (int j = 0; j < 8; ++j) {
            const int cb = (q << 2) + (j << 4);
            float4 va = v[j];
            float4 w0 = *(const float4*)(wpt + 0 * D_DIM + cb);
            float4 w1 = *(const float4*)(wpt + 1 * D_DIM + cb);
            float4 w2 = *(const float4*)(wpt + 2 * D_DIM + cb);
            float4 w3 = *(const float4*)(wpt + 3 * D_DIM + cb);
            s0 += va.x * w0.x + va.y * w0.y + va.z * w0.z + va.w * w0.w;
            s1 += va.x * w1.x + va.y * w1.y + va.z * w1.z + va.w * w1.w;
            s2 += va.x * w2.x + va.y * w2.y + va.z * w2.z + va.w * w2.w;
            s3 += va.x * w3.x + va.y * w3.y + va.z * w3.z + va.w * w3.w;
            *(float4*)(tile + wtile + r * TPAD + cb) = va;
        }

        // --- prefetch next chunk (stays in flight: no barrier ahead) ---
        float4 vn[8];
        if (c < 3) {
            const float* rp = table + (long long)ids[c + 1] * D_DIM + (q << 2);
            #pragma unroll
            for (int j = 0; j < 8; ++j) vn[j] = *(const float4*)(rp + j * 16);
        }

        // --- combine 4 q-lanes of the row; exp ---
        s0 += __shfl_xor(s0, 1); s0 += __shfl_xor(s0, 2);
        s1 += __shfl_xor(s1, 1); s1 += __shfl_xor(s1, 2);
        s2 += __shfl_xor(s2, 1); s2 += __shfl_xor(s2, 2);
        s3 += __shfl_xor(s3, 1); s3 += __shfl_xor(s3, 2);
        float e0 = expf(s0), e1 = expf(s1), e2 = expf(s2), e3 = expf(s3);
        if (q == 0) ((float4*)exps4)[w * 16 + r] = make_float4(e0, e1, e2, e3);
        lsum[0] += e0; lsum[1] += e1; lsum[2] += e2; lsum[3] += e3;

        // --- pooling over my wave's 16 chunk rows (wave-local LDS) ---
        #pragma unroll
        for (int h = 0; h < 16; ++h) {
            float4 e4 = ((const float4*)exps4)[w * 16 + h];   // broadcast
            float  p0 = tile[wtile + h * TPAD + d0];
            float  p1 = tile[wtile + h * TPAD + d1];
            accA[0] += e4.x * p0; accA[1] += e4.y * p0;
            accA[2] += e4.z * p0; accA[3] += e4.w * p0;
            accB[0] += e4.x * p1; accB[1] += e4.y * p1;
            accB[2] += e4.z * p1; accB[3] += e4.w * p1;
        }

        if (c < 3) {
            #pragma unroll
            for (int j = 0; j < 8; ++j) v[j] = vn[j];
        }
    }

    // --- wave-partial denominator: sum 16 r-classes (q-copies identical) ---
    #pragma unroll
    for (int off = 4; off <= 32; off <<= 1) {
        lsum[0] += __shfl_xor(lsum[0], off);
        lsum[1] += __shfl_xor(lsum[1], off);
        lsum[2] += __shfl_xor(lsum[2], off);
        lsum[3] += __shfl_xor(lsum[3], off);
    }

    // --- write wave partials into own tile region; one true barrier ---
    float* Pw = tile + wtile;   // 512 floats: P[w][dim] as float4 per dim
    ((float4*)Pw)[d0] = make_float4(accA[0], accA[1], accA[2], accA[3]);
    ((float4*)Pw)[d1] = make_float4(accB[0], accB[1], accB[2], accB[3]);
    if (lane == 0) ((float4*)lsumW)[w] = make_float4(lsum[0], lsum[1], lsum[2], lsum[3]);
    __syncthreads();

    // --- combine wave partials, normalize, sims ---
    float s0 = 0.f, s1 = 0.f, s2 = 0.f, s3 = 0.f;
    if (t < 128) {
        const int d = t;
        float4 p0 = ((const float4*)(tile + 0 * 16 * TPAD))[d];
        float4 p1 = ((const float4*)(tile + 1 * 16 * TPAD))[d];
        float4 p2 = ((const float4*)(tile + 2 * 16 * TPAD))[d];
        float4 p3 = ((const float4*)(tile + 3 * 16 * TPAD))[d];
        float4 L0 = ((const float4*)lsumW)[0];
        float4 L1 = ((const float4*)lsumW)[1];
        float4 L2 = ((const float4*)lsumW)[2];
        float4 L3 = ((const float4*)lsumW)[3];
        float i0 = 1.f / (L0.x + L1.x + L2.x + L3.x);
        float i1 = 1.f / (L0.y + L1.y + L2.y + L3.y);
        float i2 = 1.f / (L0.z + L1.z + L2.z + L3.z);
        float i3 = 1.f / (L0.w + L1.w + L2.w + L3.w);
        float a0 = (((p0.x + p1.x) + p2.x) + p3.x) * i0;
        float a1 = (((p0.y + p1.y) + p2.y) + p3.y) * i1;
        float a2 = (((p0.z + p1.z) + p2.z) + p3.z) * i2;
        float a3 = (((p0.w + p1.w) + p2.w) + p3.w) * i3;
        ((float4*)ivbuf)[d] = make_float4(a0, a1, a2, a3);
        float cd = candv[d];
        s0 = a0 * cd; s1 = a1 * cd; s2 = a2 * cd; s3 = a3 * cd;
    }
    #pragma unroll
    for (int off = 32; off >= 1; off >>= 1) {
        s0 += __shfl_xor(s0, off);
        s1 += __shfl_xor(s1, off);
        s2 += __shfl_xor(s2, off);
        s3 += __shfl_xor(s3, off);
    }
    if (lane == 0) {
        simred[w][0] = s0; simred[w][1] = s1;
        simred[w][2] = s2; simred[w][3] = s3;
    }
    __syncthreads();

    if (t == 0) {
        float sim[4];
        #pragma unroll
        for (int k = 0; k < 4; ++k)
            sim[k] = simred[0][k] + simred[1][k] + simred[2][k] + simred[3][k];
        int best = 0;
        #pragma unroll
        for (int k = 1; k < 4; ++k) if (sim[k] > sim[best]) best = k;  // first-max
        bestk = best;
    }
    __syncthreads();

    __hip_bfloat16* xrow = Xbf + (long long)b * (2 * D_DIM);
    if (t < 128) xrow[t] = __float2bfloat16(ivbuf[t * 4 + bestk]);
    else         xrow[t] = __float2bfloat16(candv[t - 128]);
}

// ---------------------------------------------------------------------------
// MFMA bf16 GEMM: C(M,N) = relu(A(M,K) @ B(K,N) + bias). B passed transposed
// (N,K) row-major. One wave = one 16x16 C tile; no LDS; direct b128 frag
// loads. A-frag: A[m=lane&15][k=quad*8+j]; B-frag: Bt[n=lane&15][k=quad*8+j];
// C: col=lane&15, row=quad*4+reg (verified layouts).
// ---------------------------------------------------------------------------
template<int N, int K, bool OUT_BF16>
__global__ __launch_bounds__(256) void mfma_mlp(
    const __hip_bfloat16* __restrict__ A,    // (M, K)
    const __hip_bfloat16* __restrict__ Bt,   // (N, K)
    const float* __restrict__ bias,          // (N,)
    void* __restrict__ Cout)                 // (M, N)
{
    const int t    = threadIdx.x;
    const int wave = t >> 6, lane = t & 63;
    const int lm   = lane & 15, quad = lane >> 4;
    const int n0   = blockIdx.x * 16;
    const int m0   = blockIdx.y * 64 + wave * 16;

    const __hip_bfloat16* Ap = A  + (long long)(m0 + lm) * K + quad * 8;
    const __hip_bfloat16* Bp = Bt + (long long)(n0 + lm) * K + quad * 8;

    f32x4 acc = {0.f, 0.f, 0.f, 0.f};
    for (int kc = 0; kc < K; kc += 256) {
        bf16x8 af[8], bfr[8];
        #pragma unroll
        for (int it = 0; it < 8; ++it) {
            af[it]  = *(const bf16x8*)(Ap + kc + it * 32);
            bfr[it] = *(const bf16x8*)(Bp + kc + it * 32);
        }
        #pragma unroll
        for (int it = 0; it < 8; ++it)
            acc = __builtin_amdgcn_mfma_f32_16x16x32_bf16(af[it], bfr[it], acc, 0, 0, 0);
    }

    const int n  = n0 + lm;
    const float bv = bias[n];
    #pragma unroll
    for (int i = 0; i < 4; ++i) {
        int m = m0 + quad * 4 + i;
        float v = fmaxf(acc[i] + bv, 0.f);
        if (OUT_BF16)
            ((__hip_bfloat16*)Cout)[(long long)m * N + n] = __float2bfloat16(v);
        else
            ((float*)Cout)[(long long)m * N + n] = v;
    }
}

// ---------------------------------------------------------------------------
// Kernel 4: out[b] = sigmoid(h2[b] . W3 + b3)
// ---------------------------------------------------------------------------
__global__ __launch_bounds__(256) void head_kernel(
    const float* __restrict__ H2buf,   // (B, 256) fp32
    const float* __restrict__ W3,      // (256, 1)
    const float* __restrict__ b3,
    float*       __restrict__ out)     // (B,)
{
    const int b = blockIdx.x * 256 + threadIdx.x;
    const float4* hp = (const float4*)(H2buf + (long long)b * H2_DIM);
    const float4* wp = (const float4*)W3;
    float acc = 0.f;
    #pragma unroll 8
    for (int i = 0; i < H2_DIM / 4; ++i) {
        float4 h = hp[i], wv = wp[i];
        acc += h.x * wv.x + h.y * wv.y + h.z * wv.z + h.w * wv.w;
    }
    float z = acc + b3[0];
    out[b] = 1.f / (1.f + expf(-z));
}

// ---------------------------------------------------------------------------
extern "C" void kernel_launch(void* const* d_in, const int* in_sizes, int n_in,
                              void* d_out, int out_size, void* d_ws, size_t ws_size,
                              hipStream_t stream) {
    const int*   cand  = (const int*)  d_in[1];
    const int*   hist  = (const int*)  d_in[2];
    const float* table = (const float*)d_in[3];
    const float* Wp    = (const float*)d_in[4];
    const float* W1    = (const float*)d_in[5];
    const float* b1    = (const float*)d_in[6];
    const float* W2    = (const float*)d_in[7];
    const float* b2    = (const float*)d_in[8];
    const float* W3    = (const float*)d_in[9];
    const float* b3    = (const float*)d_in[10];
    float* out = (float*)d_out;

    // ws layout (16B-aligned regions)
    char* p = (char*)d_ws;
    __hip_bfloat16* Xbf  = (__hip_bfloat16*)p;                  p += (size_t)B_SZ * 2 * D_DIM * 2;  // 2 MB
    __hip_bfloat16* Hc1  = (__hip_bfloat16*)p;                  p += (size_t)B_SZ * H1_DIM * 2;     // 4 MB
    float*          Hc2  = (float*)p;                           p += (size_t)B_SZ * H2_DIM * 4;     // 4 MB
    __hip_bfloat16* W1t  = (__hip_bfloat16*)p;                  p += (size_t)H1_DIM * 2 * D_DIM * 2;// 512 KB
    __hip_bfloat16* W2t  = (__hip_bfloat16*)p;                                                      // 512 KB

    // interest blocks [0,4096) + weight-convert blocks [4096,5120)
    interest_kernel<<<B_SZ + 1024, 256, 0, stream>>>(
        cand, hist, table, Wp, W1, W2, W1t, W2t, Xbf);
    mfma_mlp<H1_DIM, 2 * D_DIM, true><<<dim3(H1_DIM / 16, B_SZ / 64), 256, 0, stream>>>(
        Xbf, W1t, b1, Hc1);
    mfma_mlp<H2_DIM, H1_DIM, false><<<dim3(H2_DIM / 16, B_SZ / 64), 256, 0, stream>>>(
        Hc1, W2t, b2, Hc2);
    head_kernel<<<B_SZ / 256, 256, 0, stream>>>(Hc2, W3, b3, out);
}

// Round 8
// 297.108 us; speedup vs baseline: 2.4578x; 1.8005x over previous
//
#include <hip/hip_runtime.h>
#include <hip/hip_bf16.h>
#include <math.h>

#define B_SZ   4096
#define H_LEN  256
#define D_DIM  128
#define K_HEADS 4
#define H1_DIM 512
#define H2_DIM 256

#define CH     64     // history rows per chunk (round-3/5 config: fastest measured)
#define NCH    4      // chunks
#define TPAD   132    // tile row stride (floats): 16B-aligned
#define H1PAD  520    // H1 LDS row stride (bf16): breaks 1024B power-of-2 stride

typedef __attribute__((ext_vector_type(8))) short bf16x8;   // 8 bf16 (4 VGPRs)
typedef __attribute__((ext_vector_type(4))) float f32x4;

// ---------------------------------------------------------------------------
// Kernel 1: multi-interest extraction, round-5 body exactly (107 us, VGPR 64,
// no spill). Blocks [0,4096): sample b. Blocks [4096,5120): bf16 weight
// transpose for the MFMA tail. Interest = beyond-L2 random-gather bound
// (255 MB at ~2.4 TB/s LLC service rate) -- structural floor.
// ---------------------------------------------------------------------------
__global__ __launch_bounds__(256, 4) void interest_kernel(
    const int*   __restrict__ cand_ids,   // (B,)
    const int*   __restrict__ hist,       // (B, H)
    const float* __restrict__ table,      // (NUM_ITEMS, D)
    const float* __restrict__ Wp,         // (D, K) row-major
    const float* __restrict__ W1,         // (2D, H1)
    const float* __restrict__ W2,         // (H1, H2)
    __hip_bfloat16* __restrict__ W1t,     // out (H1, 2D) bf16
    __hip_bfloat16* __restrict__ W2t,     // out (H2, H1) bf16
    __hip_bfloat16* __restrict__ Xbf)     // out (B, 2D) bf16: [selected | cand]
{
    // ---- weight-conversion blocks ----
    if (blockIdx.x >= B_SZ) {
        int idx = (blockIdx.x - B_SZ) * 256 + threadIdx.x;
        if (idx < 2 * D_DIM * H1_DIM) {              // W1t[n][k] = W1[k][n]
            int n = idx >> 8, k = idx & 255;
            W1t[idx] = __float2bfloat16(W1[k * H1_DIM + n]);
        } else {                                     // W2t[n][k] = W2[k][n]
            int j = idx - 2 * D_DIM * H1_DIM;
            int n = j >> 9, k = j & 511;
            W2t[j] = __float2bfloat16(W2[k * H2_DIM + n]);
        }
        return;
    }

    __shared__ float tile[CH * TPAD];     // 33792 B; tail-reused for partB/ivbuf
    __shared__ float wpt[K_HEADS * D_DIM];// Wp^T [k][d]           2 KB
    __shared__ float exps4[CH * 4];       // exp(score) [h][k]     1 KB
    __shared__ float candv[D_DIM];        //                       512 B
    __shared__ int   rowids[H_LEN];       //                       1 KB
    __shared__ float lsumW[16];           // per-wave denom partials [w][k]
    __shared__ float simred[4][K_HEADS];
    __shared__ int   bestk;

    const int b    = blockIdx.x;
    const int t    = threadIdx.x;
    const int lane = t & 63, w = t >> 6;
    const int r    = t >> 2, q = t & 3;      // gather: 4 threads per row
    const int d    = t & 127, half = t >> 7; // pooling: 2 threads per d

    if (t < D_DIM) {
        float4 w4 = ((const float4*)Wp)[t];   // Wp[d=t][0..3]
        wpt[0 * D_DIM + t] = w4.x;
        wpt[1 * D_DIM + t] = w4.y;
        wpt[2 * D_DIM + t] = w4.z;
        wpt[3 * D_DIM + t] = w4.w;
    }
    const int cand = cand_ids[b];
    if (t >= 128 && t < 160) {
        int c = t - 128;
        ((float4*)candv)[c] = ((const float4*)(table + (long long)cand * D_DIM))[c];
    }
    rowids[t] = hist[(long long)b * H_LEN + t];

    float a0 = 0.f, a1 = 0.f, a2 = 0.f, a3 = 0.f;  // pooling acc for (d,half)
    float l0 = 0.f, l1 = 0.f, l2 = 0.f, l3 = 0.f;  // wave-local denom partials

    for (int c = 0; c < NCH; ++c) {
        __syncthreads();   // tile/exps4 free (and staging ready on c==0)

        // --- gather 64 rows; thread (r,q) owns float4 columns q+4j ---
        const int   row = rowids[(c << 6) + r];
        const float* rp = table + (long long)row * D_DIM + (q << 2);
        float4 v0 = *(const float4*)(rp + 0 * 16);
        float4 v1 = *(const float4*)(rp + 1 * 16);
        float4 v2 = *(const float4*)(rp + 2 * 16);
        float4 v3 = *(const float4*)(rp + 3 * 16);
        float4 v4 = *(const float4*)(rp + 4 * 16);
        float4 v5 = *(const float4*)(rp + 5 * 16);
        float4 v6 = *(const float4*)(rp + 6 * 16);
        float4 v7 = *(const float4*)(rp + 7 * 16);

        float s0 = 0.f, s1 = 0.f, s2 = 0.f, s3 = 0.f;
        float4 va;
        #define DO_J(J, VV)                                                     \
        {   va = VV;                                                            \
            const int cb = (q << 2) + (J << 4);                                 \
            float4 w0 = *(const float4*)(wpt + 0 * D_DIM + cb);                 \
            float4 w1 = *(const float4*)(wpt + 1 * D_DIM + cb);                 \
            float4 w2 = *(const float4*)(wpt + 2 * D_DIM + cb);                 \
            float4 w3 = *(const float4*)(wpt + 3 * D_DIM + cb);                 \
            s0 += va.x * w0.x + va.y * w0.y + va.z * w0.z + va.w * w0.w;        \
            s1 += va.x * w1.x + va.y * w1.y + va.z * w1.z + va.w * w1.w;        \
            s2 += va.x * w2.x + va.y * w2.y + va.z * w2.z + va.w * w2.w;        \
            s3 += va.x * w3.x + va.y * w3.y + va.z * w3.z + va.w * w3.w;        \
            *(float4*)(tile + r * TPAD + cb) = va;                              \
        }
        DO_J(0, v0) DO_J(1, v1) DO_J(2, v2) DO_J(3, v3)
        DO_J(4, v4) DO_J(5, v5) DO_J(6, v6) DO_J(7, v7)
        #undef DO_J

        // combine the 4 q-lanes of each row
        s0 += __shfl_xor(s0, 1); s0 += __shfl_xor(s0, 2);
        s1 += __shfl_xor(s1, 1); s1 += __shfl_xor(s1, 2);
        s2 += __shfl_xor(s2, 1); s2 += __shfl_xor(s2, 2);
        s3 += __shfl_xor(s3, 1); s3 += __shfl_xor(s3, 2);

        float e0 = expf(s0), e1 = expf(s1), e2 = expf(s2), e3 = expf(s3);
        if (q == 0) ((float4*)exps4)[r] = make_float4(e0, e1, e2, e3);

        // wave-sum over this wave's 16 rows
        float t0 = e0, t1 = e1, t2 = e2, t3 = e3;
        #pragma unroll
        for (int off = 4; off <= 32; off <<= 1) {
            t0 += __shfl_xor(t0, off);
            t1 += __shfl_xor(t1, off);
            t2 += __shfl_xor(t2, off);
            t3 += __shfl_xor(t3, off);
        }
        l0 += t0; l1 += t1; l2 += t2; l3 += t3;

        __syncthreads();   // tile + exps4 visible

        // --- pooling: acc[k][d] += sum over my 32 chunk rows ---
        #pragma unroll 8
        for (int i = 0; i < 32; ++i) {
            int hl = (half << 5) + i;
            float4 e4 = ((const float4*)exps4)[hl];   // broadcast
            float  vv = tile[hl * TPAD + d];
            a0 += e4.x * vv; a1 += e4.y * vv; a2 += e4.z * vv; a3 += e4.w * vv;
        }
    }

    __syncthreads();   // tile reads done -> reuse tile memory
    float* partBp = tile;         // 512 floats
    float* ivbufp = tile + 512;   // 512 floats

    if (half == 1) ((float4*)partBp)[d] = make_float4(a0, a1, a2, a3);
    if (lane == 0) ((float4*)lsumW)[w]  = make_float4(l0, l1, l2, l3);
    __syncthreads();

    float s0 = 0.f, s1 = 0.f, s2 = 0.f, s3 = 0.f;
    if (half == 0) {
        float4 pb = ((const float4*)partBp)[d];
        float4 L0 = ((const float4*)lsumW)[0];
        float4 L1 = ((const float4*)lsumW)[1];
        float4 L2 = ((const float4*)lsumW)[2];
        float4 L3 = ((const float4*)lsumW)[3];
        float i0 = 1.f / (L0.x + L1.x + L2.x + L3.x);
        float i1 = 1.f / (L0.y + L1.y + L2.y + L3.y);
        float i2 = 1.f / (L0.z + L1.z + L2.z + L3.z);
        float i3 = 1.f / (L0.w + L1.w + L2.w + L3.w);
        a0 = (a0 + pb.x) * i0;
        a1 = (a1 + pb.y) * i1;
        a2 = (a2 + pb.z) * i2;
        a3 = (a3 + pb.w) * i3;
        ((float4*)ivbufp)[d] = make_float4(a0, a1, a2, a3);
        float cd = candv[d];
        s0 = a0 * cd; s1 = a1 * cd; s2 = a2 * cd; s3 = a3 * cd;
    }
    #pragma unroll
    for (int off = 32; off >= 1; off >>= 1) {
        s0 += __shfl_xor(s0, off);
        s1 += __shfl_xor(s1, off);
        s2 += __shfl_xor(s2, off);
        s3 += __shfl_xor(s3, off);
    }
    if (lane == 0) {
        simred[w][0] = s0; simred[w][1] = s1;
        simred[w][2] = s2; simred[w][3] = s3;
    }
    __syncthreads();

    if (t == 0) {
        float sim[4];
        #pragma unroll
        for (int k = 0; k < 4; ++k)
            sim[k] = simred[0][k] + simred[1][k] + simred[2][k] + simred[3][k];
        int best = 0;
        #pragma unroll
        for (int k = 1; k < 4; ++k) if (sim[k] > sim[best]) best = k;  // first-max
        bestk = best;
    }
    __syncthreads();

    __hip_bfloat16* xrow = Xbf + (long long)b * (2 * D_DIM);
    if (t < 128) xrow[t] = __float2bfloat16(ivbufp[t * 4 + bestk]);
    else         xrow[t] = __float2bfloat16(candv[t - 128]);
}

// ---------------------------------------------------------------------------
// Fused MLP tail: one kernel = layer1 (relu) -> LDS -> layer2 (relu) -> head
// dot + sigmoid. 64 blocks x 64 rows; wave w owns m-tile rows [16w,16w+16)
// end-to-end (wave-private -> ZERO barriers). A-frags preloaded once and
// reused across all n-tiles. MFMA layouts: A[m=lane&15][k=quad*8+j],
// B=Wt[n=lane&15][k=quad*8+j], C col=lane&15 row=quad*4+reg (verified).
// ---------------------------------------------------------------------------
__global__ __launch_bounds__(256) void fused_mlp(
    const __hip_bfloat16* __restrict__ Xbf,   // (B, 256)
    const __hip_bfloat16* __restrict__ W1t,   // (512, 256)
    const float* __restrict__ b1,
    const __hip_bfloat16* __restrict__ W2t,   // (256, 512)
    const float* __restrict__ b2,
    const float* __restrict__ W3,             // (256, 1)
    const float* __restrict__ b3,
    float* __restrict__ out)                  // (B,)
{
    __shared__ __hip_bfloat16 H1s[64 * H1PAD];   // 66560 B

    const int t    = threadIdx.x;
    const int wave = t >> 6, lane = t & 63;
    const int lm   = lane & 15, quad = lane >> 4;
    const int mrow = blockIdx.x * 64 + wave * 16;  // global row base of my tile
    const int lrow = wave * 16;                    // LDS row base

    // ---- layer 1: H1[m][n] = relu(X @ W1 + b1) for my 16 rows ----
    const __hip_bfloat16* Ap = Xbf + (long long)(mrow + lm) * 256 + quad * 8;
    bf16x8 afr[8];
    #pragma unroll
    for (int j = 0; j < 8; ++j) afr[j] = *(const bf16x8*)(Ap + j * 32);

    #pragma unroll 4
    for (int nt = 0; nt < 32; ++nt) {
        const int n = nt * 16 + lm;
        const __hip_bfloat16* Bp = W1t + (long long)n * 256 + quad * 8;
        f32x4 acc = {0.f, 0.f, 0.f, 0.f};
        #pragma unroll
        for (int j = 0; j < 8; ++j) {
            bf16x8 bfr = *(const bf16x8*)(Bp + j * 32);
            acc = __builtin_amdgcn_mfma_f32_16x16x32_bf16(afr[j], bfr, acc, 0, 0, 0);
        }
        const float bv = b1[n];
        #pragma unroll
        for (int i = 0; i < 4; ++i) {
            float v = fmaxf(acc[i] + bv, 0.f);
            H1s[(lrow + quad * 4 + i) * H1PAD + n] = __float2bfloat16(v);
        }
    }

    // ---- layer 2 + head (wave-private rows: no barrier needed) ----
    bf16x8 hfr[16];
    #pragma unroll
    for (int j = 0; j < 16; ++j)
        hfr[j] = *(const bf16x8*)(&H1s[(lrow + lm) * H1PAD + j * 32 + quad * 8]);

    float hp[4] = {0.f, 0.f, 0.f, 0.f};
    #pragma unroll 2
    for (int nt = 0; nt < 16; ++nt) {
        const int n = nt * 16 + lm;
        const __hip_bfloat16* Bp = W2t + (long long)n * 512 + quad * 8;
        f32x4 acc = {0.f, 0.f, 0.f, 0.f};
        #pragma unroll
        for (int j = 0; j < 16; ++j) {
            bf16x8 bfr = *(const bf16x8*)(Bp + j * 32);
            acc = __builtin_amdgcn_mfma_f32_16x16x32_bf16(hfr[j], bfr, acc, 0, 0, 0);
        }
        const float bv = b2[n], w3v = W3[n];
        #pragma unroll
        for (int i = 0; i < 4; ++i)
            hp[i] += fmaxf(acc[i] + bv, 0.f) * w3v;
    }

    // reduce across the 16 n-lanes (xor 1,2,4,8 keeps quad bits fixed)
    #pragma unroll
    for (int off = 1; off <= 8; off <<= 1) {
        hp[0] += __shfl_xor(hp[0], off);
        hp[1] += __shfl_xor(hp[1], off);
        hp[2] += __shfl_xor(hp[2], off);
        hp[3] += __shfl_xor(hp[3], off);
    }
    if (lm == 0) {
        const float bb = b3[0];
        #pragma unroll
        for (int i = 0; i < 4; ++i) {
            float z = hp[i] + bb;
            out[mrow + quad * 4 + i] = 1.f / (1.f + expf(-z));
        }
    }
}

// ---------------------------------------------------------------------------
extern "C" void kernel_launch(void* const* d_in, const int* in_sizes, int n_in,
                              void* d_out, int out_size, void* d_ws, size_t ws_size,
                              hipStream_t stream) {
    const int*   cand  = (const int*)  d_in[1];
    const int*   hist  = (const int*)  d_in[2];
    const float* table = (const float*)d_in[3];
    const float* Wp    = (const float*)d_in[4];
    const float* W1    = (const float*)d_in[5];
    const float* b1    = (const float*)d_in[6];
    const float* W2    = (const float*)d_in[7];
    const float* b2    = (const float*)d_in[8];
    const float* W3    = (const float*)d_in[9];
    const float* b3    = (const float*)d_in[10];
    float* out = (float*)d_out;

    // ws layout (16B-aligned regions)
    char* p = (char*)d_ws;
    __hip_bfloat16* Xbf = (__hip_bfloat16*)p;  p += (size_t)B_SZ * 2 * D_DIM * 2;   // 2 MB
    __hip_bfloat16* W1t = (__hip_bfloat16*)p;  p += (size_t)H1_DIM * 2 * D_DIM * 2; // 512 KB
    __hip_bfloat16* W2t = (__hip_bfloat16*)p;                                        // 512 KB

    // interest blocks [0,4096) + weight-convert blocks [4096,5120)
    interest_kernel<<<B_SZ + 1024, 256, 0, stream>>>(
        cand, hist, table, Wp, W1, W2, W1t, W2t, Xbf);
    fused_mlp<<<B_SZ / 64, 256, 0, stream>>>(Xbf, W1t, b1, W2t, b2, W3, b3, out);
}